// Round 11
// baseline (753.774 us; speedup 1.0000x reference)
//
#include <hip/hip_runtime.h>
#include <math.h>

// Problem constants (hard-coded from setup_inputs)
#define B_N 4
#define S_N 2048
#define D_N 1024
#define H_N 16
#define HD_N 64
#define M_N (B_N * S_N)   // 8192

typedef __attribute__((ext_vector_type(8))) short bf16x8;   // 8 bf16 = 4 VGPRs (MFMA A/B frag)
typedef __attribute__((ext_vector_type(4))) float f32x4;    // MFMA C/D frag

// bf16 round-to-nearest-even split helpers
static __device__ __forceinline__ unsigned short f2bf(float f) {
    unsigned int u = __float_as_uint(f);
    u += 0x7FFF + ((u >> 16) & 1);
    return (unsigned short)(u >> 16);
}
static __device__ __forceinline__ float bf2f(unsigned short h) {
    return __uint_as_float(((unsigned int)h) << 16);
}

// ---------------------------------------------------------------------------
// Kernel 1: RoPE cos/sin table (S_N x 32)
// ---------------------------------------------------------------------------
__global__ __launch_bounds__(256)
void rope_table_kernel(float* __restrict__ cos_t, float* __restrict__ sin_t) {
    int idx = blockIdx.x * 256 + threadIdx.x;
    if (idx >= S_N * 32) return;
    int sp = idx >> 5;
    int p  = idx & 31;
    float inv = powf(10000.0f, -(float)p / 32.0f);
    float ang = (float)sp * inv;
    float s, c;
    sincosf(ang, &s, &c);
    cos_t[idx] = c;
    sin_t[idx] = s;
}

// ---------------------------------------------------------------------------
// Kernel 2: weight transpose-split.  W[mat] (1024x1024 f32, [k][n]) ->
// WTh/WTl bf16 [4096][1024] with row = mat*1024 + n, col = k.
// ---------------------------------------------------------------------------
__global__ __launch_bounds__(256)
void splitT_w_kernel(const float* __restrict__ W0, const float* __restrict__ W1,
                     const float* __restrict__ W2, const float* __restrict__ W3,
                     unsigned short* __restrict__ WTh, unsigned short* __restrict__ WTl)
{
    __shared__ float tile[64][65];
    const int k0  = blockIdx.x * 64;
    const int n0  = blockIdx.y * 64;
    const int mat = blockIdx.z;
    const float* __restrict__ W = (mat == 0) ? W0 : (mat == 1) ? W1 : (mat == 2) ? W2 : W3;
    const int t = threadIdx.x;

    #pragma unroll
    for (int p = 0; p < 4; ++p) {
        int idx = t + p * 256;
        int r = idx >> 4, c4 = (idx & 15) * 4;
        float4 v = *(const float4*)&W[(size_t)(k0 + r) * D_N + n0 + c4];
        tile[r][c4]     = v.x;
        tile[r][c4 + 1] = v.y;
        tile[r][c4 + 2] = v.z;
        tile[r][c4 + 3] = v.w;
    }
    __syncthreads();
    #pragma unroll
    for (int p = 0; p < 4; ++p) {
        int idx = t + p * 256;
        int nl = idx >> 4, kc = (idx & 15) * 4;
        ushort4 hi, lo;
        float f0 = tile[kc][nl], f1 = tile[kc + 1][nl];
        float f2 = tile[kc + 2][nl], f3 = tile[kc + 3][nl];
        hi.x = f2bf(f0); lo.x = f2bf(f0 - bf2f(hi.x));
        hi.y = f2bf(f1); lo.y = f2bf(f1 - bf2f(hi.y));
        hi.z = f2bf(f2); lo.z = f2bf(f2 - bf2f(hi.z));
        hi.w = f2bf(f3); lo.w = f2bf(f3 - bf2f(hi.w));
        size_t base = ((size_t)(mat * D_N + n0 + nl)) * D_N + k0 + kc;
        *(ushort4*)&WTh[base] = hi;
        *(ushort4*)&WTl[base] = lo;
    }
}

// ---------------------------------------------------------------------------
// Shared MFMA GEMM core: 128x128 C-tile, BK=32, 4 waves (2x2), split-bf16
// 3-term (Ah*Bh + Al*Bh + Ah*Bl).  Unchanged from validated round 6.
// ---------------------------------------------------------------------------
__device__ __forceinline__ void gemm_core_f32A(
    const float* __restrict__ A,
    const unsigned short* __restrict__ Bh, const unsigned short* __restrict__ Bl,
    int aRow0, int bRow0,
    unsigned short* ldsA, unsigned short* ldsB,
    f32x4 acc[4][4])
{
    const int tid  = threadIdx.x;
    const int wave = tid >> 6;
    const int lane = tid & 63;
    const int l15  = lane & 15;
    const int lg   = lane >> 4;
    const int wr   = wave >> 1;
    const int wc   = wave & 1;

    const float* ga[2];
    int la[2];
    #pragma unroll
    for (int p = 0; p < 2; ++p) {
        int c = tid + p * 256;
        int row = c >> 2, kc = c & 3;
        ga[p] = A + (size_t)(aRow0 + row) * D_N + kc * 8;
        la[p] = row * 72 + kc * 8;
    }
    const unsigned short* gb[4];
    int lb[4];
    #pragma unroll
    for (int p = 0; p < 4; ++p) {
        int c = tid + p * 256;
        int row = c >> 3, ss = c & 7, sel = ss >> 2, kc = ss & 3;
        gb[p] = (sel ? Bl : Bh) + (size_t)(bRow0 + row) * D_N + kc * 8;
        lb[p] = row * 72 + ss * 8;
    }

    for (int kk = 0; kk < D_N / 32; ++kk) {
        float4 av[2][2];
        bf16x8 bv[4];
        #pragma unroll
        for (int p = 0; p < 2; ++p) {
            av[p][0] = *(const float4*)ga[p];
            av[p][1] = *(const float4*)(ga[p] + 4);
            ga[p] += 32;
        }
        #pragma unroll
        for (int p = 0; p < 4; ++p) {
            bv[p] = *(const bf16x8*)gb[p];
            gb[p] += 32;
        }
        __syncthreads();
        #pragma unroll
        for (int p = 0; p < 2; ++p) {
            bf16x8 hi, lo;
            float v[8] = {av[p][0].x, av[p][0].y, av[p][0].z, av[p][0].w,
                          av[p][1].x, av[p][1].y, av[p][1].z, av[p][1].w};
            #pragma unroll
            for (int q = 0; q < 8; ++q) {
                unsigned short h = f2bf(v[q]);
                hi[q] = (short)h;
                lo[q] = (short)f2bf(v[q] - bf2f(h));
            }
            *(bf16x8*)&ldsA[la[p]]      = hi;
            *(bf16x8*)&ldsA[la[p] + 32] = lo;
        }
        #pragma unroll
        for (int p = 0; p < 4; ++p)
            *(bf16x8*)&ldsB[lb[p]] = bv[p];
        __syncthreads();

        bf16x8 ah[4], al[4], bh[4], bl[4];
        #pragma unroll
        for (int i = 0; i < 4; ++i) {
            int ar = wr * 64 + i * 16 + l15;
            ah[i] = *(const bf16x8*)&ldsA[ar * 72 + lg * 8];
            al[i] = *(const bf16x8*)&ldsA[ar * 72 + 32 + lg * 8];
            int br = wc * 64 + i * 16 + l15;
            bh[i] = *(const bf16x8*)&ldsB[br * 72 + lg * 8];
            bl[i] = *(const bf16x8*)&ldsB[br * 72 + 32 + lg * 8];
        }
        #pragma unroll
        for (int i = 0; i < 4; ++i)
            #pragma unroll
            for (int j = 0; j < 4; ++j) {
                acc[i][j] = __builtin_amdgcn_mfma_f32_16x16x32_bf16(ah[i], bh[j], acc[i][j], 0, 0, 0);
                acc[i][j] = __builtin_amdgcn_mfma_f32_16x16x32_bf16(al[i], bh[j], acc[i][j], 0, 0, 0);
                acc[i][j] = __builtin_amdgcn_mfma_f32_16x16x32_bf16(ah[i], bl[j], acc[i][j], 0, 0, 0);
            }
    }
}

// ---------------------------------------------------------------------------
// Kernel 3: QKV MFMA GEMM + bias + RoPE + hi/lo split-scatter epilogue.
// Unchanged from validated round 6.
// ---------------------------------------------------------------------------
__global__ __launch_bounds__(256)
void qkv_gemm_kernel(const float* __restrict__ x,
                     const unsigned short* __restrict__ WTh, const unsigned short* __restrict__ WTl,
                     const float* __restrict__ bq, const float* __restrict__ bk,
                     const float* __restrict__ bv_,
                     const float* __restrict__ cos_t, const float* __restrict__ sin_t,
                     unsigned short* __restrict__ Qh, unsigned short* __restrict__ Ql,
                     unsigned short* __restrict__ Kh, unsigned short* __restrict__ Kl,
                     unsigned short* __restrict__ Vth, unsigned short* __restrict__ Vtl)
{
    __shared__ unsigned short ldsA[128 * 72];
    __shared__ unsigned short ldsB[128 * 72];

    const int m0  = blockIdx.x * 128;
    const int n0  = blockIdx.y * 128;
    const int mat = n0 >> 10;

    f32x4 acc[4][4];
    #pragma unroll
    for (int i = 0; i < 4; ++i)
        #pragma unroll
        for (int j = 0; j < 4; ++j) acc[i][j] = (f32x4){0.f, 0.f, 0.f, 0.f};

    gemm_core_f32A(x, WTh, WTl, m0, n0, ldsA, ldsB, acc);

    const int tid  = threadIdx.x;
    const int wave = tid >> 6;
    const int lane = tid & 63;
    const int l15  = lane & 15;
    const int lg   = lane >> 4;
    const int wr   = wave >> 1;
    const int wc   = wave & 1;

    const float* __restrict__ bias = (mat == 0) ? bq : (mat == 1) ? bk : bv_;
    unsigned short* __restrict__ Hi = (mat == 0) ? Qh : Kh;
    unsigned short* __restrict__ Lo = (mat == 0) ? Ql : Kl;

    #pragma unroll
    for (int i = 0; i < 4; ++i) {
        #pragma unroll
        for (int j = 0; j < 4; ++j) {
            const int nl   = (n0 & 1023) + wc * 64 + j * 16 + l15;
            const int head = nl >> 6;
            const int d    = nl & 63;
            const float bval = bias[nl];
            const int m_base = m0 + wr * 64 + i * 16 + lg * 4;
            const int bb  = m_base >> 11;
            const int sp0 = m_base & (S_N - 1);

            if (mat == 2) {
                ushort4 hi4, lo4;
                float v0 = acc[i][j][0] + bval;
                float v1 = acc[i][j][1] + bval;
                float v2 = acc[i][j][2] + bval;
                float v3 = acc[i][j][3] + bval;
                hi4.x = f2bf(v0); lo4.x = f2bf(v0 - bf2f(hi4.x));
                hi4.y = f2bf(v1); lo4.y = f2bf(v1 - bf2f(hi4.y));
                hi4.z = f2bf(v2); lo4.z = f2bf(v2 - bf2f(hi4.z));
                hi4.w = f2bf(v3); lo4.w = f2bf(v3 - bf2f(hi4.w));
                size_t base = ((size_t)((bb * H_N + head) * HD_N + d)) * S_N + sp0;
                *(ushort4*)&Vth[base] = hi4;
                *(ushort4*)&Vtl[base] = lo4;
            } else {
                const int p = d >> 1;
                const float sgn = (d & 1) ? 1.0f : -1.0f;
                #pragma unroll
                for (int r = 0; r < 4; ++r) {
                    int sp = sp0 + r;
                    float v = acc[i][j][r] + bval;
                    float part = __shfl_xor(v, 1);
                    float c = cos_t[sp * 32 + p];
                    float s = sin_t[sp * 32 + p];
                    float vp = v * c + part * s * sgn;
                    if (mat == 0) vp *= 0.125f;
                    unsigned short hi = f2bf(vp);
                    unsigned short lo = f2bf(vp - bf2f(hi));
                    size_t base = ((size_t)((bb * H_N + head) * S_N + sp)) * HD_N + d;
                    Hi[base] = hi;
                    Lo[base] = lo;
                }
            }
        }
    }
}

// ---------------------------------------------------------------------------
// Kernel 4: flash attention, split-bf16 MFMA.  32 q-rows per wave, T5 setprio
// (validated r10).  NEW (T14): K/V staging loads for tile kt+1 are issued as
// loop-carried register prefetch right after the post-staging barrier, so
// HBM/L2 latency hides under the QK/softmax/PV compute phase.  The compiler's
// vmcnt(0) drain before the top-of-loop barrier is the completion point.
// grid = (S/128, H, B), 256 threads.
// ---------------------------------------------------------------------------
__global__ __launch_bounds__(256)
void attn_kernel(const unsigned short* __restrict__ Qh, const unsigned short* __restrict__ Ql,
                 const unsigned short* __restrict__ Kh, const unsigned short* __restrict__ Kl,
                 const unsigned short* __restrict__ Vh, const unsigned short* __restrict__ Vl,
                 float* __restrict__ O)
{
    __shared__ __align__(16) unsigned short KhS[4096];
    __shared__ __align__(16) unsigned short KlS[4096];
    __shared__ __align__(16) unsigned short VhS[4096];
    __shared__ __align__(16) unsigned short VlS[4096];
    __shared__ __align__(16) unsigned short Pb[4][2048];   // per-wave P tile [32][64]

    const int qt = blockIdx.x;   // 0..15
    const int h  = blockIdx.y;
    const int b  = blockIdx.z;
    const int bh = b * H_N + h;

    const int tid  = threadIdx.x;
    const int wave = tid >> 6;
    const int lane = tid & 63;
    const int l15  = lane & 15;
    const int lg   = lane >> 4;

    // Q fragments for two 16-row blocks (rb=0,1)
    bf16x8 qfh[2][2], qfl[2][2];
    #pragma unroll
    for (int rb = 0; rb < 2; ++rb) {
        const int qrow = qt * 128 + wave * 32 + rb * 16 + l15;
        const size_t qbase = ((size_t)bh * S_N + qrow) * HD_N;
        qfh[rb][0] = *(const bf16x8*)&Qh[qbase + lg * 8];
        qfh[rb][1] = *(const bf16x8*)&Qh[qbase + 32 + lg * 8];
        qfl[rb][0] = *(const bf16x8*)&Ql[qbase + lg * 8];
        qfl[rb][1] = *(const bf16x8*)&Ql[qbase + 32 + lg * 8];
    }

    f32x4 oacc[2][4];
    float m_r[2][4], l_r[2][4];
    #pragma unroll
    for (int rb = 0; rb < 2; ++rb) {
        #pragma unroll
        for (int dt = 0; dt < 4; ++dt) oacc[rb][dt] = (f32x4){0.f, 0.f, 0.f, 0.f};
        #pragma unroll
        for (int r = 0; r < 4; ++r) { m_r[rb][r] = -1e30f; l_r[rb][r] = 0.f; }
    }

    // Staging geometry (2 x 16B chunks per thread) + kt=0 register prefetch
    const int NT = S_N / 64;
    int liA[2];
    size_t gkBase[2], gvBase[2];
    #pragma unroll
    for (int t = 0; t < 2; ++t) {
        int c = tid + t * 256;
        int row = c >> 3, sl = c & 7;
        liA[t] = (row * 64 + sl * 8) ^ ((row & 7) << 3);
        gkBase[t] = (size_t)bh * S_N * HD_N + (size_t)row * HD_N + sl * 8;
        gvBase[t] = (size_t)bh * HD_N * S_N + (size_t)row * S_N + sl * 8;
    }
    bf16x8 rkh[2], rkl[2], rvh[2], rvl[2];
    #pragma unroll
    for (int t = 0; t < 2; ++t) {
        rkh[t] = *(const bf16x8*)&Kh[gkBase[t]];
        rkl[t] = *(const bf16x8*)&Kl[gkBase[t]];
        rvh[t] = *(const bf16x8*)&Vh[gvBase[t]];
        rvl[t] = *(const bf16x8*)&Vl[gvBase[t]];
    }

    for (int kt = 0; kt < NT; ++kt) {
        __syncthreads();   // prior tile's readers done (also drains prefetch vmcnt)
        #pragma unroll
        for (int t = 0; t < 2; ++t) {
            *(bf16x8*)&KhS[liA[t]] = rkh[t];
            *(bf16x8*)&KlS[liA[t]] = rkl[t];
            *(bf16x8*)&VhS[liA[t]] = rvh[t];
            *(bf16x8*)&VlS[liA[t]] = rvl[t];
        }
        __syncthreads();

        // issue next tile's global loads now; they fly during QK/softmax/PV
        {
            int ktn = (kt + 1 < NT) ? kt + 1 : kt;   // clamp: last-iter data unused
            size_t dk = (size_t)ktn * 64 * HD_N;
            size_t dv = (size_t)ktn * 64;
            #pragma unroll
            for (int t = 0; t < 2; ++t) {
                rkh[t] = *(const bf16x8*)&Kh[gkBase[t] + dk];
                rkl[t] = *(const bf16x8*)&Kl[gkBase[t] + dk];
                rvh[t] = *(const bf16x8*)&Vh[gvBase[t] + dv];
                rvl[t] = *(const bf16x8*)&Vl[gvBase[t] + dv];
            }
        }

        // S = Q K^T, both row-blocks share each K fragment read
        f32x4 s[2][4];
        #pragma unroll
        for (int rb = 0; rb < 2; ++rb)
            #pragma unroll
            for (int nt = 0; nt < 4; ++nt) s[rb][nt] = (f32x4){0.f, 0.f, 0.f, 0.f};
        __builtin_amdgcn_s_setprio(1);
        #pragma unroll
        for (int ks = 0; ks < 2; ++ks) {
            #pragma unroll
            for (int nt = 0; nt < 4; ++nt) {
                int row = nt * 16 + l15;
                int bi  = (row * 64 + ks * 32 + lg * 8) ^ ((row & 7) << 3);
                bf16x8 fkh = *(const bf16x8*)&KhS[bi];
                bf16x8 fkl = *(const bf16x8*)&KlS[bi];
                #pragma unroll
                for (int rb = 0; rb < 2; ++rb) {
                    s[rb][nt] = __builtin_amdgcn_mfma_f32_16x16x32_bf16(qfh[rb][ks], fkh, s[rb][nt], 0, 0, 0);
                    s[rb][nt] = __builtin_amdgcn_mfma_f32_16x16x32_bf16(qfl[rb][ks], fkh, s[rb][nt], 0, 0, 0);
                    s[rb][nt] = __builtin_amdgcn_mfma_f32_16x16x32_bf16(qfh[rb][ks], fkl, s[rb][nt], 0, 0, 0);
                }
            }
        }
        __builtin_amdgcn_s_setprio(0);

        // online softmax per row-block; C layout: row = lg*4+r, col = nt*16+l15
        #pragma unroll
        for (int rb = 0; rb < 2; ++rb) {
            #pragma unroll
            for (int r = 0; r < 4; ++r) {
                float mx = fmaxf(fmaxf(s[rb][0][r], s[rb][1][r]), fmaxf(s[rb][2][r], s[rb][3][r]));
                mx = fmaxf(mx, __shfl_xor(mx, 1));
                mx = fmaxf(mx, __shfl_xor(mx, 2));
                mx = fmaxf(mx, __shfl_xor(mx, 4));
                mx = fmaxf(mx, __shfl_xor(mx, 8));
                float mnew = fmaxf(m_r[rb][r], mx);
                float al   = __expf(m_r[rb][r] - mnew);
                float ps   = 0.f;
                #pragma unroll
                for (int nt = 0; nt < 4; ++nt) {
                    float p = __expf(s[rb][nt][r] - mnew);
                    s[rb][nt][r] = p;
                    ps += p;
                }
                ps += __shfl_xor(ps, 1);
                ps += __shfl_xor(ps, 2);
                ps += __shfl_xor(ps, 4);
                ps += __shfl_xor(ps, 8);
                l_r[rb][r] = l_r[rb][r] * al + ps;
                m_r[rb][r] = mnew;
                oacc[rb][0][r] *= al; oacc[rb][1][r] *= al;
                oacc[rb][2][r] *= al; oacc[rb][3][r] *= al;
                int prow = rb * 16 + lg * 4 + r;
                #pragma unroll
                for (int nt = 0; nt < 4; ++nt) {
                    Pb[wave][(prow * 64 + nt * 16 + l15) ^ ((prow & 7) << 3)] = f2bf(s[rb][nt][r]);
                }
            }
        }
        // wave-private buffer: LDS completion order only, no cross-wave barrier
        asm volatile("s_waitcnt lgkmcnt(0)" ::: "memory");

        // O += P @ V : V fragments shared across both row-blocks
        __builtin_amdgcn_s_setprio(1);
        #pragma unroll
        for (int ks = 0; ks < 2; ++ks) {
            int pr0 = l15;
            int pr1 = 16 + l15;
            bf16x8 pa0 = *(const bf16x8*)&Pb[wave][(pr0 * 64 + ks * 32 + lg * 8) ^ ((pr0 & 7) << 3)];
            bf16x8 pa1 = *(const bf16x8*)&Pb[wave][(pr1 * 64 + ks * 32 + lg * 8) ^ ((pr1 & 7) << 3)];
            #pragma unroll
            for (int dt = 0; dt < 4; ++dt) {
                int vrow = dt * 16 + l15;
                int vbi  = (vrow * 64 + ks * 32 + lg * 8) ^ ((vrow & 7) << 3);
                bf16x8 fvh = *(const bf16x8*)&VhS[vbi];
                bf16x8 fvl = *(const bf16x8*)&VlS[vbi];
                oacc[0][dt] = __builtin_amdgcn_mfma_f32_16x16x32_bf16(pa0, fvh, oacc[0][dt], 0, 0, 0);
                oacc[0][dt] = __builtin_amdgcn_mfma_f32_16x16x32_bf16(pa0, fvl, oacc[0][dt], 0, 0, 0);
                oacc[1][dt] = __builtin_amdgcn_mfma_f32_16x16x32_bf16(pa1, fvh, oacc[1][dt], 0, 0, 0);
                oacc[1][dt] = __builtin_amdgcn_mfma_f32_16x16x32_bf16(pa1, fvl, oacc[1][dt], 0, 0, 0);
            }
        }
        __builtin_amdgcn_s_setprio(0);
    }

    // normalize + store fp32 to [B,S,A]
    #pragma unroll
    for (int rb = 0; rb < 2; ++rb) {
        #pragma unroll
        for (int r = 0; r < 4; ++r) {
            float inv = 1.0f / l_r[rb][r];
            int row = qt * 128 + wave * 32 + rb * 16 + lg * 4 + r;
            size_t obase = ((size_t)b * S_N + row) * D_N + h * HD_N;
            #pragma unroll
            for (int dt = 0; dt < 4; ++dt)
                O[obase + dt * 16 + l15] = oacc[rb][dt][r] * inv;
        }
    }
}

// ---------------------------------------------------------------------------
// Kernel 5: output projection via split-bf16 MFMA.  Unchanged from round 6.
// ---------------------------------------------------------------------------
__global__ __launch_bounds__(256)
void out_gemm_kernel(const float* __restrict__ A,
                     const unsigned short* __restrict__ WTh, const unsigned short* __restrict__ WTl,
                     const float* __restrict__ bo, float* __restrict__ out)
{
    __shared__ unsigned short ldsA[128 * 72];
    __shared__ unsigned short ldsB[128 * 72];

    const int m0 = blockIdx.x * 128;
    const int n0 = blockIdx.y * 128;

    f32x4 acc[4][4];
    #pragma unroll
    for (int i = 0; i < 4; ++i)
        #pragma unroll
        for (int j = 0; j < 4; ++j) acc[i][j] = (f32x4){0.f, 0.f, 0.f, 0.f};

    gemm_core_f32A(A, WTh, WTl, m0, 3 * D_N + n0, ldsA, ldsB, acc);

    const int tid  = threadIdx.x;
    const int wave = tid >> 6;
    const int lane = tid & 63;
    const int l15  = lane & 15;
    const int lg   = lane >> 4;
    const int wr   = wave >> 1;
    const int wc   = wave & 1;

    #pragma unroll
    for (int i = 0; i < 4; ++i) {
        #pragma unroll
        for (int j = 0; j < 4; ++j) {
            int n = n0 + wc * 64 + j * 16 + l15;
            float bval = bo[n];
            int m_base = m0 + wr * 64 + i * 16 + lg * 4;
            #pragma unroll
            for (int r = 0; r < 4; ++r)
                out[(size_t)(m_base + r) * D_N + n] = acc[i][j][r] + bval;
        }
    }
}

// ---------------------------------------------------------------------------
extern "C" void kernel_launch(void* const* d_in, const int* in_sizes, int n_in,
                              void* d_out, int out_size, void* d_ws, size_t ws_size,
                              hipStream_t stream) {
    const float* x  = (const float*)d_in[0];
    const float* Wq = (const float*)d_in[1];
    const float* bq = (const float*)d_in[2];
    const float* Wk = (const float*)d_in[3];
    const float* bk = (const float*)d_in[4];
    const float* Wv = (const float*)d_in[5];
    const float* bv = (const float*)d_in[6];
    const float* Wo = (const float*)d_in[7];
    const float* bo = (const float*)d_in[8];
    float* out = (float*)d_out;

    const size_t NE = (size_t)B_N * H_N * S_N * HD_N;   // 8388608 per split matrix
    const size_t WTE = (size_t)4 * D_N * D_N;           // 4194304

    float* cos_t = (float*)d_ws;
    float* sin_t = cos_t + (size_t)S_N * 32;
    unsigned short* WTh = (unsigned short*)(sin_t + (size_t)S_N * 32);
    unsigned short* WTl = WTh + WTE;
    unsigned short* Qh  = WTl + WTE;
    unsigned short* Ql  = Qh  + NE;
    unsigned short* Kh  = Ql  + NE;
    unsigned short* Kl  = Kh  + NE;
    unsigned short* Vth = Kl  + NE;
    unsigned short* Vtl = Vth + NE;
    float* Obuf = (float*)(Vtl + NE);
    // total ws: 0.5 + 16 + 96 + 32 = 144.5 MB

    rope_table_kernel<<<256, 256, 0, stream>>>(cos_t, sin_t);

    dim3 gw(16, 16, 4);
    splitT_w_kernel<<<gw, 256, 0, stream>>>(Wq, Wk, Wv, Wo, WTh, WTl);

    dim3 g1(M_N / 128, 24);
    qkv_gemm_kernel<<<g1, 256, 0, stream>>>(x, WTh, WTl, bq, bk, bv,
                                            cos_t, sin_t,
                                            Qh, Ql, Kh, Kl, Vth, Vtl);

    dim3 g2(S_N / 128, H_N, B_N);
    attn_kernel<<<g2, 256, 0, stream>>>(Qh, Ql, Kh, Kl, Vth, Vtl, Obuf);

    dim3 g3(M_N / 128, 8);
    out_gemm_kernel<<<g3, 256, 0, stream>>>(Obuf, WTh, WTl, bo, out);
}